// Round 8
// baseline (403.608 us; speedup 1.0000x reference)
//
#include <hip/hip_runtime.h>
#include <hip/hip_bf16.h>

// B=2, L=2048, D=1024, H=16, dh=64. fp32 in/out.
// out = softmax((qa@Wq/8) @ (ma@Wk)^T + bias) @ (ma@Wv) @ Wo.
// Round 8: (1) transposed attention — S^T C-layout feeds mfma_16x16x16bf16_1k
// B-operand directly from registers (Ps LDS round-trip deleted); (2) QKV GEMM
// stores V^T (8B packed) so attn V staging is b128; (3) GEMMs use m97-style
// global_load_lds width-16 staging.

typedef __attribute__((ext_vector_type(8))) short short8;    // 8 x bf16 (4 VGPR)
typedef __attribute__((ext_vector_type(4))) short short4v;   // 4 x bf16 (2 VGPR)
typedef __attribute__((ext_vector_type(4))) float float4v;   // 4 x f32

#define LSEQ 2048
#define DMODEL 1024
#define MROWS 4096   // B*L

#define GLDS(g, l) __builtin_amdgcn_global_load_lds(                        \
    (const __attribute__((address_space(1))) void*)(g),                     \
    (__attribute__((address_space(3))) void*)(l), 16, 0, 0)

// ---------------------------------------------------------------------------
// fp32 -> bf16 bulk convert (qa, ma). grid (2048, 2)
// ---------------------------------------------------------------------------
__global__ __launch_bounds__(256)
void convert_kernel(const float* __restrict__ qa, const float* __restrict__ ma,
                    __hip_bfloat16* __restrict__ qo, __hip_bfloat16* __restrict__ mo)
{
    const size_t i = ((size_t)blockIdx.x * 256 + threadIdx.x) * 8;
    const float* src = blockIdx.y ? ma : qa;
    __hip_bfloat16* dst = blockIdx.y ? mo : qo;
    float4 v0 = *reinterpret_cast<const float4*>(src + i);
    float4 v1 = *reinterpret_cast<const float4*>(src + i + 4);
    union { __hip_bfloat16 h[8]; int4 v; } pk;
    pk.h[0] = (__hip_bfloat16)v0.x; pk.h[1] = (__hip_bfloat16)v0.y;
    pk.h[2] = (__hip_bfloat16)v0.z; pk.h[3] = (__hip_bfloat16)v0.w;
    pk.h[4] = (__hip_bfloat16)v1.x; pk.h[5] = (__hip_bfloat16)v1.y;
    pk.h[6] = (__hip_bfloat16)v1.z; pk.h[7] = (__hip_bfloat16)v1.w;
    *reinterpret_cast<int4*>(dst + i) = pk.v;
}

// ---------------------------------------------------------------------------
// Weight transpose+convert: W[K][N] f32 -> Wt[N][K] bf16. 64x64 tiles.
// grid (16,16,4): z=0..2 -> Wq/Wk/Wv into Wt[3072][1024]; z=3 -> Wot.
// ---------------------------------------------------------------------------
__global__ __launch_bounds__(256)
void transpose_w_kernel(const float* __restrict__ W0, const float* __restrict__ W1,
                        const float* __restrict__ W2, const float* __restrict__ W3,
                        __hip_bfloat16* __restrict__ T0, __hip_bfloat16* __restrict__ T1,
                        __hip_bfloat16* __restrict__ T2, __hip_bfloat16* __restrict__ T3)
{
    __shared__ __hip_bfloat16 T[64][68];

    const float* W; __hip_bfloat16* D;
    if      (blockIdx.z == 0) { W = W0; D = T0; }
    else if (blockIdx.z == 1) { W = W1; D = T1; }
    else if (blockIdx.z == 2) { W = W2; D = T2; }
    else                      { W = W3; D = T3; }

    const int t  = threadIdx.x;
    const int n0 = blockIdx.x * 64;
    const int k0 = blockIdx.y * 64;

#pragma unroll
    for (int p = 0; p < 4; ++p) {
        const int r = p * 16 + (t >> 4);
        const int c = (t & 15) * 4;
        float4 v = *reinterpret_cast<const float4*>(&W[(size_t)(k0 + r) * DMODEL + n0 + c]);
        union { __hip_bfloat16 h[4]; ushort4 v; } pk;
        pk.h[0] = (__hip_bfloat16)v.x; pk.h[1] = (__hip_bfloat16)v.y;
        pk.h[2] = (__hip_bfloat16)v.z; pk.h[3] = (__hip_bfloat16)v.w;
        *reinterpret_cast<ushort4*>(&T[r][c]) = pk.v;
    }
    __syncthreads();
#pragma unroll
    for (int p = 0; p < 2; ++p) {
        const int n  = p * 32 + (t & 31);
        const int kc = (t >> 5) * 8;
        union { __hip_bfloat16 h[8]; int4 v; } pk;
#pragma unroll
        for (int j = 0; j < 8; ++j) pk.h[j] = T[kc + j][n];
        *reinterpret_cast<int4*>(&D[(size_t)(n0 + n) * DMODEL + k0 + kc]) = pk.v;
    }
}

// ---------------------------------------------------------------------------
// Fused QKV GEMM, m97-style global_load_lds staging. 128x128 tile, BK=32.
// C cols [0,1024)=Q*0.125 -> Qw row-major; [1024,2048)=K -> Kw row-major;
// [2048,3072)=V -> VTw TRANSPOSED [b*16+h][d][seq] (8B packed stores).
// ---------------------------------------------------------------------------
__global__ __launch_bounds__(256)
void gemm_qkv_kernel(const __hip_bfloat16* __restrict__ qa16,
                     const __hip_bfloat16* __restrict__ ma16,
                     const __hip_bfloat16* __restrict__ Wt,   // [3072][1024]
                     __hip_bfloat16* __restrict__ Qw,         // [4096][1024]
                     __hip_bfloat16* __restrict__ Kw,         // [4096][1024]
                     __hip_bfloat16* __restrict__ VTw)        // [32][64][2048]
{
    __shared__ __hip_bfloat16 As[128 * 32];   // unpadded: global_load_lds layout
    __shared__ __hip_bfloat16 Bs[128 * 32];

    const int t    = threadIdx.x;
    const int w    = t >> 6;
    const int lane = t & 63;
    const int l15  = lane & 15;
    const int lq   = lane >> 4;
    const int m0   = blockIdx.y * 128;
    const int n0   = blockIdx.x * 128;
    const int wm   = (w >> 1) * 64;
    const int wn   = (w & 1) * 64;
    const int srow = lane >> 2;          // staging row within 16-row chunk
    const int scol = (lane & 3) * 8;     // staging col (elems)

    const __hip_bfloat16* A = (n0 < 1024) ? qa16 : ma16;

    float4v acc[4][4];
#pragma unroll
    for (int mi = 0; mi < 4; ++mi)
#pragma unroll
        for (int ni = 0; ni < 4; ++ni) acc[mi][ni] = (float4v){0.f, 0.f, 0.f, 0.f};

    for (int k0 = 0; k0 < 1024; k0 += 32) {
        __syncthreads();   // prior frag reads done before LDS overwrite
#pragma unroll
        for (int i = 0; i < 2; ++i) {
            const int rr = (w * 2 + i) * 16 + srow;
            GLDS(A  + (size_t)(m0 + rr) * 1024 + k0 + scol, &As[(w * 2 + i) * 512]);
            GLDS(Wt + (size_t)(n0 + rr) * 1024 + k0 + scol, &Bs[(w * 2 + i) * 512]);
        }
        asm volatile("s_waitcnt vmcnt(0)" ::: "memory");
        __syncthreads();

        short8 af[4], bf[4];
#pragma unroll
        for (int mi = 0; mi < 4; ++mi)
            af[mi] = *reinterpret_cast<const short8*>(&As[(wm + mi * 16 + l15) * 32 + lq * 8]);
#pragma unroll
        for (int ni = 0; ni < 4; ++ni)
            bf[ni] = *reinterpret_cast<const short8*>(&Bs[(wn + ni * 16 + l15) * 32 + lq * 8]);
#pragma unroll
        for (int mi = 0; mi < 4; ++mi)
#pragma unroll
            for (int ni = 0; ni < 4; ++ni)
                acc[mi][ni] = __builtin_amdgcn_mfma_f32_16x16x32_bf16(
                    af[mi], bf[ni], acc[mi][ni], 0, 0, 0);
    }

    if (n0 < 2048) {
        // Q / K: row-major bf16
        __hip_bfloat16* C = (n0 < 1024) ? Qw : Kw;
        const int   nb = (n0 < 1024) ? n0 : n0 - 1024;
        const float al = (n0 < 1024) ? 0.125f : 1.0f;
#pragma unroll
        for (int mi = 0; mi < 4; ++mi)
#pragma unroll
            for (int ni = 0; ni < 4; ++ni)
#pragma unroll
                for (int r = 0; r < 4; ++r) {
                    const int row = m0 + wm + mi * 16 + lq * 4 + r;
                    const int col = nb + wn + ni * 16 + l15;
                    C[(size_t)row * 1024 + col] = (__hip_bfloat16)(acc[mi][ni][r] * al);
                }
    } else {
        // V: transposed 8B-packed stores -> VTw[(b*16+h)*64+d][seq]
#pragma unroll
        for (int mi = 0; mi < 4; ++mi) {
            const int rowbase = m0 + wm + mi * 16 + lq * 4;
            const int b   = rowbase >> 11;
            const int seq = rowbase & 2047;
#pragma unroll
            for (int ni = 0; ni < 4; ++ni) {
                const int n = n0 - 2048 + wn + ni * 16 + l15;
                const int h = n >> 6, d = n & 63;
                union { __hip_bfloat16 hh[4]; uint2 v; } pk;
#pragma unroll
                for (int r = 0; r < 4; ++r) pk.hh[r] = (__hip_bfloat16)acc[mi][ni][r];
                *reinterpret_cast<uint2*>(
                    &VTw[((size_t)(b * 16 + h) * 64 + d) * 2048 + seq]) = pk.v;
            }
        }
    }
}

// ---------------------------------------------------------------------------
// Output GEMM: out = X @ Wo, fp32 out. Same m97 staging. grid (8, 32).
// ---------------------------------------------------------------------------
__global__ __launch_bounds__(256)
void gemm_out_kernel(const __hip_bfloat16* __restrict__ Xw,   // [4096][1024]
                     const __hip_bfloat16* __restrict__ Wot,  // [1024][1024]
                     float* __restrict__ out)
{
    __shared__ __hip_bfloat16 As[128 * 32];
    __shared__ __hip_bfloat16 Bs[128 * 32];

    const int t    = threadIdx.x;
    const int w    = t >> 6;
    const int lane = t & 63;
    const int l15  = lane & 15;
    const int lq   = lane >> 4;
    const int m0   = blockIdx.y * 128;
    const int n0   = blockIdx.x * 128;
    const int wm   = (w >> 1) * 64;
    const int wn   = (w & 1) * 64;
    const int srow = lane >> 2;
    const int scol = (lane & 3) * 8;

    float4v acc[4][4];
#pragma unroll
    for (int mi = 0; mi < 4; ++mi)
#pragma unroll
        for (int ni = 0; ni < 4; ++ni) acc[mi][ni] = (float4v){0.f, 0.f, 0.f, 0.f};

    for (int k0 = 0; k0 < 1024; k0 += 32) {
        __syncthreads();
#pragma unroll
        for (int i = 0; i < 2; ++i) {
            const int rr = (w * 2 + i) * 16 + srow;
            GLDS(Xw  + (size_t)(m0 + rr) * 1024 + k0 + scol, &As[(w * 2 + i) * 512]);
            GLDS(Wot + (size_t)(n0 + rr) * 1024 + k0 + scol, &Bs[(w * 2 + i) * 512]);
        }
        asm volatile("s_waitcnt vmcnt(0)" ::: "memory");
        __syncthreads();

        short8 af[4], bf[4];
#pragma unroll
        for (int mi = 0; mi < 4; ++mi)
            af[mi] = *reinterpret_cast<const short8*>(&As[(wm + mi * 16 + l15) * 32 + lq * 8]);
#pragma unroll
        for (int ni = 0; ni < 4; ++ni)
            bf[ni] = *reinterpret_cast<const short8*>(&Bs[(wn + ni * 16 + l15) * 32 + lq * 8]);
#pragma unroll
        for (int mi = 0; mi < 4; ++mi)
#pragma unroll
            for (int ni = 0; ni < 4; ++ni)
                acc[mi][ni] = __builtin_amdgcn_mfma_f32_16x16x32_bf16(
                    af[mi], bf[ni], acc[mi][ni], 0, 0, 0);
    }

#pragma unroll
    for (int mi = 0; mi < 4; ++mi)
#pragma unroll
        for (int ni = 0; ni < 4; ++ni)
#pragma unroll
            for (int r = 0; r < 4; ++r) {
                const int row = m0 + wm + mi * 16 + lq * 4 + r;
                const int col = n0 + wn + ni * 16 + l15;
                out[(size_t)row * 1024 + col] = acc[mi][ni][r];
            }
}

// ---------------------------------------------------------------------------
// Transposed MFMA flash attention, no-max softmax. Grid 512 (XCD swizzle),
// 256 threads = 4 waves; wave w: q-rows [w*32,w*32+32) as 2 groups of 16.
// S^T = K·Q^T via 16x16x32 (A=K-frag, B=Q-frag — same LDS reads as before).
// S^T C-layout (row=key=lq*4+r, col=q=l15) == B-frag layout of
// mfma_f32_16x16x16bf16_1k (k=lq*4+j, n=l15): P^T feeds PV from REGISTERS.
// O^T = V^T·P^T accumulated in C-layout (row=d, col=q); V^T from VTw (b128
// staging, b64 A-frag reads). Bias: float4 (4 contiguous keys per lane).
// ---------------------------------------------------------------------------
__global__ __launch_bounds__(256)
void attn_kernel(const __hip_bfloat16* __restrict__ Qw,   // [4096][1024]
                 const __hip_bfloat16* __restrict__ Kw,   // [4096][1024]
                 const __hip_bfloat16* __restrict__ VTw,  // [32][64][2048]
                 const float* __restrict__ bias,          // [2048][2048] f32
                 __hip_bfloat16* __restrict__ X)          // [4096][1024]
{
    __shared__ __hip_bfloat16 Ks[128][72];   // [key][dh]
    __shared__ __hip_bfloat16 Vt[64][136];   // [d][key]

    const int t   = threadIdx.x;
    const int w   = t >> 6;
    const int l15 = t & 15;
    const int lq  = (t & 63) >> 4;

    // XCD swizzle: pin each (b,h)'s 16 q-tiles to one XCD class
    const int bid = blockIdx.x;
    const int r8  = bid & 7;
    const int j   = bid >> 3;
    const int bh  = r8 + 8 * (j >> 4);
    const int q0  = (j & 15) * 128;
    const int b   = bh >> 4;
    const int h   = bh & 15;

    const __hip_bfloat16* Kb  = Kw + (size_t)b * LSEQ * 1024 + h * 64;
    const __hip_bfloat16* VTb = VTw + ((size_t)(b * 16 + h) * 64) * 2048;

    // Q as B-fragments (lane l15 = q-row, lq*8+j = dh) — loop-invariant
    short8 bq[2][2];
#pragma unroll
    for (int g = 0; g < 2; ++g) {
        const __hip_bfloat16* qrow = Qw +
            (size_t)(b * LSEQ + q0 + w * 32 + g * 16 + l15) * 1024 + h * 64 + lq * 8;
        bq[g][0] = *reinterpret_cast<const short8*>(qrow);
        bq[g][1] = *reinterpret_cast<const short8*>(qrow + 32);
    }

    float lpart[2] = {0.f, 0.f};
    float4v o[2][4];
#pragma unroll
    for (int g = 0; g < 2; ++g)
#pragma unroll
        for (int mi = 0; mi < 4; ++mi) o[g][mi] = (float4v){0.f, 0.f, 0.f, 0.f};

    // staging: K: thread t -> key rnd*64 + (t>>2), dh (t&3)*16
    //          V: thread t -> d = t>>2, keys (t&3)*32 + {0,8,16,24}
    const int skey = t >> 2;
    const int sdh  = (t & 3) * 16;
    const int vd   = t >> 2;
    const int vk   = (t & 3) * 32;

    int4 pk_[2][2], pv_[4];
#pragma unroll
    for (int rnd = 0; rnd < 2; ++rnd) {
        const __hip_bfloat16* ks = Kb + (size_t)(rnd * 64 + skey) * 1024 + sdh;
        pk_[rnd][0] = *reinterpret_cast<const int4*>(ks);
        pk_[rnd][1] = *reinterpret_cast<const int4*>(ks + 8);
    }
#pragma unroll
    for (int c = 0; c < 4; ++c)
        pv_[c] = *reinterpret_cast<const int4*>(VTb + (size_t)vd * 2048 + vk + c * 8);

    for (int kt = 0; kt < LSEQ / 128; ++kt) {
        const int k0 = kt * 128;
        __syncthreads();   // prev tile's frag reads done
#pragma unroll
        for (int rnd = 0; rnd < 2; ++rnd) {
            *reinterpret_cast<int4*>(&Ks[rnd * 64 + skey][sdh])     = pk_[rnd][0];
            *reinterpret_cast<int4*>(&Ks[rnd * 64 + skey][sdh + 8]) = pk_[rnd][1];
        }
#pragma unroll
        for (int c = 0; c < 4; ++c)
            *reinterpret_cast<int4*>(&Vt[vd][vk + c * 8]) = pv_[c];
        // prefetch next tile (clamped re-load on last iter)
        {
            const int kn = (kt + 1 < LSEQ / 128) ? k0 + 128 : k0;
#pragma unroll
            for (int rnd = 0; rnd < 2; ++rnd) {
                const __hip_bfloat16* ks = Kb + (size_t)(kn + rnd * 64 + skey) * 1024 + sdh;
                pk_[rnd][0] = *reinterpret_cast<const int4*>(ks);
                pk_[rnd][1] = *reinterpret_cast<const int4*>(ks + 8);
            }
#pragma unroll
            for (int c = 0; c < 4; ++c)
                pv_[c] = *reinterpret_cast<const int4*>(VTb + (size_t)vd * 2048 + kn + vk + c * 8);
        }
        __syncthreads();

        // S^T = K·Q^T : 32 MFMA (K A-frags shared across groups)
        float4v s[2][8];
#pragma unroll
        for (int c = 0; c < 8; ++c) {
            s[0][c] = (float4v){0.f, 0.f, 0.f, 0.f};
            s[1][c] = (float4v){0.f, 0.f, 0.f, 0.f};
        }
#pragma unroll
        for (int c = 0; c < 8; ++c) {
            short8 ka0 = *reinterpret_cast<const short8*>(&Ks[c * 16 + l15][lq * 8]);
            short8 ka1 = *reinterpret_cast<const short8*>(&Ks[c * 16 + l15][32 + lq * 8]);
            s[0][c] = __builtin_amdgcn_mfma_f32_16x16x32_bf16(ka0, bq[0][0], s[0][c], 0, 0, 0);
            s[0][c] = __builtin_amdgcn_mfma_f32_16x16x32_bf16(ka1, bq[0][1], s[0][c], 0, 0, 0);
            s[1][c] = __builtin_amdgcn_mfma_f32_16x16x32_bf16(ka0, bq[1][0], s[1][c], 0, 0, 0);
            s[1][c] = __builtin_amdgcn_mfma_f32_16x16x32_bf16(ka1, bq[1][1], s[1][c], 0, 0, 0);
        }

        // p = exp(s + bias), packed to P^T B-frags in registers
        short4v pb[2][8];
#pragma unroll
        for (int g = 0; g < 2; ++g) {
            const float* bp = bias +
                (size_t)(q0 + w * 32 + g * 16 + l15) * LSEQ + k0 + lq * 4;
#pragma unroll
            for (int c = 0; c < 8; ++c) {
                float4 bvv = *reinterpret_cast<const float4*>(bp + c * 16);
                const float* bv = reinterpret_cast<const float*>(&bvv);
                union { __hip_bfloat16 hh[4]; short4v v; } pkk;
                float acc_l = 0.f;
#pragma unroll
                for (int r = 0; r < 4; ++r) {
                    const float p = __expf(s[g][c][r] + bv[r]);
                    acc_l += p;
                    pkk.hh[r] = (__hip_bfloat16)p;
                }
                lpart[g] += acc_l;
                pb[g][c] = pkk.v;
            }
        }

        // O^T += V^T · P^T : 64 MFMA K=16 (V A-frags shared across groups)
#pragma unroll
        for (int mi = 0; mi < 4; ++mi) {
#pragma unroll
            for (int kk = 0; kk < 8; ++kk) {
                short4v va = *reinterpret_cast<const short4v*>(
                    &Vt[mi * 16 + l15][kk * 16 + lq * 4]);
                o[0][mi] = __builtin_amdgcn_mfma_f32_16x16x16bf16_1k(
                    va, pb[0][kk], o[0][mi], 0, 0, 0);
                o[1][mi] = __builtin_amdgcn_mfma_f32_16x16x16bf16_1k(
                    va, pb[1][kk], o[1][mi], 0, 0, 0);
            }
        }
    }

    // l: sum over quads (rows=keys live in lq), then normalize + 8B stores
#pragma unroll
    for (int g = 0; g < 2; ++g) {
        float lp = lpart[g];
        lp += __shfl_xor(lp, 16);
        lp += __shfl_xor(lp, 32);
        const float inv = 1.f / lp;
        const size_t xrow = (size_t)(b * LSEQ + q0 + w * 32 + g * 16 + l15) * 1024;
#pragma unroll
        for (int mi = 0; mi < 4; ++mi) {
            union { __hip_bfloat16 hh[4]; uint2 v; } pkk;
#pragma unroll
            for (int r = 0; r < 4; ++r) pkk.hh[r] = (__hip_bfloat16)(o[g][mi][r] * inv);
            *reinterpret_cast<uint2*>(&X[xrow + h * 64 + mi * 16 + lq * 4]) = pkk.v;
        }
    }
}

// ---------------------------------------------------------------------------
extern "C" void kernel_launch(void* const* d_in, const int* in_sizes, int n_in,
                              void* d_out, int out_size, void* d_ws, size_t ws_size,
                              hipStream_t stream)
{
    const float* qa   = (const float*)d_in[0];
    const float* ma   = (const float*)d_in[1];
    const float* bias = (const float*)d_in[2];
    const float* Wq   = (const float*)d_in[3];
    const float* Wk   = (const float*)d_in[4];
    const float* Wv   = (const float*)d_in[5];
    const float* Wo   = (const float*)d_in[6];
    float* out = (float*)d_out;

    // ws (48 MB): [0,8) qa16/Xw | [8,16) ma16 | [16,22) Wt | [22,24) Wot |
    //             [24,32) Qw | [32,40) Kw | [40,48) VTw
    char* wsb = (char*)d_ws;
    __hip_bfloat16* qa16 = (__hip_bfloat16*)(wsb);
    __hip_bfloat16* ma16 = (__hip_bfloat16*)(wsb + (8u  << 20));
    __hip_bfloat16* Wt   = (__hip_bfloat16*)(wsb + (16u << 20));
    __hip_bfloat16* Wot  = (__hip_bfloat16*)(wsb + (22u << 20));
    __hip_bfloat16* Qw   = (__hip_bfloat16*)(wsb + (24u << 20));
    __hip_bfloat16* Kw   = (__hip_bfloat16*)(wsb + (32u << 20));
    __hip_bfloat16* VTw  = (__hip_bfloat16*)(wsb + (40u << 20));
    __hip_bfloat16* Xw   = qa16;   // qa16 dead after QKV GEMM

    convert_kernel<<<dim3(MROWS * DMODEL / (256 * 8), 2), 256, 0, stream>>>(
        qa, ma, qa16, ma16);

    transpose_w_kernel<<<dim3(16, 16, 4), 256, 0, stream>>>(
        Wq, Wk, Wv, Wo,
        Wt, Wt + (size_t)DMODEL * DMODEL, Wt + 2 * (size_t)DMODEL * DMODEL, Wot);

    gemm_qkv_kernel<<<dim3(3072 / 128, MROWS / 128), 256, 0, stream>>>(
        qa16, ma16, Wt, Qw, Kw, VTw);

    attn_kernel<<<dim3(512), 256, 0, stream>>>(Qw, Kw, VTw, bias, Xw);

    gemm_out_kernel<<<dim3(1024 / 128, MROWS / 128), 256, 0, stream>>>(
        Xw, Wot, out);
}

// Round 9
// 371.821 us; speedup vs baseline: 1.0855x; 1.0855x over previous
//
#include <hip/hip_runtime.h>
#include <hip/hip_bf16.h>

// B=2, L=2048, D=1024, H=16, dh=64. fp32 in/out.
// out = softmax((qa@Wq/8) @ (ma@Wk)^T + bias) @ (ma@Wv) @ Wo.
// Round 9 = round 8 structure with the scratch-spill fixed:
//   - attn __launch_bounds__(256,2) (VGPR cap 256, was spilling at 112)
//   - QK MFMA -> bias -> exp -> pack fused per 16-key chunk (s: 64->8 live)
// Round 8 pathology: WRITE_SIZE 269MB/dispatch = scratch traffic.

typedef __attribute__((ext_vector_type(8))) short short8;    // 8 x bf16 (4 VGPR)
typedef __attribute__((ext_vector_type(4))) short short4v;   // 4 x bf16 (2 VGPR)
typedef __attribute__((ext_vector_type(4))) float float4v;   // 4 x f32

#define LSEQ 2048
#define DMODEL 1024
#define MROWS 4096   // B*L

#define GLDS(g, l) __builtin_amdgcn_global_load_lds(                        \
    (const __attribute__((address_space(1))) void*)(g),                     \
    (__attribute__((address_space(3))) void*)(l), 16, 0, 0)

// ---------------------------------------------------------------------------
// fp32 -> bf16 bulk convert (qa, ma). grid (2048, 2)
// ---------------------------------------------------------------------------
__global__ __launch_bounds__(256)
void convert_kernel(const float* __restrict__ qa, const float* __restrict__ ma,
                    __hip_bfloat16* __restrict__ qo, __hip_bfloat16* __restrict__ mo)
{
    const size_t i = ((size_t)blockIdx.x * 256 + threadIdx.x) * 8;
    const float* src = blockIdx.y ? ma : qa;
    __hip_bfloat16* dst = blockIdx.y ? mo : qo;
    float4 v0 = *reinterpret_cast<const float4*>(src + i);
    float4 v1 = *reinterpret_cast<const float4*>(src + i + 4);
    union { __hip_bfloat16 h[8]; int4 v; } pk;
    pk.h[0] = (__hip_bfloat16)v0.x; pk.h[1] = (__hip_bfloat16)v0.y;
    pk.h[2] = (__hip_bfloat16)v0.z; pk.h[3] = (__hip_bfloat16)v0.w;
    pk.h[4] = (__hip_bfloat16)v1.x; pk.h[5] = (__hip_bfloat16)v1.y;
    pk.h[6] = (__hip_bfloat16)v1.z; pk.h[7] = (__hip_bfloat16)v1.w;
    *reinterpret_cast<int4*>(dst + i) = pk.v;
}

// ---------------------------------------------------------------------------
// Weight transpose+convert: W[K][N] f32 -> Wt[N][K] bf16. 64x64 tiles.
// grid (16,16,4): z=0..2 -> Wq/Wk/Wv into Wt[3072][1024]; z=3 -> Wot.
// ---------------------------------------------------------------------------
__global__ __launch_bounds__(256)
void transpose_w_kernel(const float* __restrict__ W0, const float* __restrict__ W1,
                        const float* __restrict__ W2, const float* __restrict__ W3,
                        __hip_bfloat16* __restrict__ T0, __hip_bfloat16* __restrict__ T1,
                        __hip_bfloat16* __restrict__ T2, __hip_bfloat16* __restrict__ T3)
{
    __shared__ __hip_bfloat16 T[64][68];

    const float* W; __hip_bfloat16* D;
    if      (blockIdx.z == 0) { W = W0; D = T0; }
    else if (blockIdx.z == 1) { W = W1; D = T1; }
    else if (blockIdx.z == 2) { W = W2; D = T2; }
    else                      { W = W3; D = T3; }

    const int t  = threadIdx.x;
    const int n0 = blockIdx.x * 64;
    const int k0 = blockIdx.y * 64;

#pragma unroll
    for (int p = 0; p < 4; ++p) {
        const int r = p * 16 + (t >> 4);
        const int c = (t & 15) * 4;
        float4 v = *reinterpret_cast<const float4*>(&W[(size_t)(k0 + r) * DMODEL + n0 + c]);
        union { __hip_bfloat16 h[4]; ushort4 v; } pk;
        pk.h[0] = (__hip_bfloat16)v.x; pk.h[1] = (__hip_bfloat16)v.y;
        pk.h[2] = (__hip_bfloat16)v.z; pk.h[3] = (__hip_bfloat16)v.w;
        *reinterpret_cast<ushort4*>(&T[r][c]) = pk.v;
    }
    __syncthreads();
#pragma unroll
    for (int p = 0; p < 2; ++p) {
        const int n  = p * 32 + (t & 31);
        const int kc = (t >> 5) * 8;
        union { __hip_bfloat16 h[8]; int4 v; } pk;
#pragma unroll
        for (int j = 0; j < 8; ++j) pk.h[j] = T[kc + j][n];
        *reinterpret_cast<int4*>(&D[(size_t)(n0 + n) * DMODEL + k0 + kc]) = pk.v;
    }
}

// ---------------------------------------------------------------------------
// Fused QKV GEMM, m97-style global_load_lds staging. 128x128 tile, BK=32.
// C cols [0,1024)=Q*0.125 -> Qw; [1024,2048)=K -> Kw; [2048,3072)=V -> VTw
// transposed [b*16+h][d][seq] (8B packed stores).
// ---------------------------------------------------------------------------
__global__ __launch_bounds__(256)
void gemm_qkv_kernel(const __hip_bfloat16* __restrict__ qa16,
                     const __hip_bfloat16* __restrict__ ma16,
                     const __hip_bfloat16* __restrict__ Wt,   // [3072][1024]
                     __hip_bfloat16* __restrict__ Qw,         // [4096][1024]
                     __hip_bfloat16* __restrict__ Kw,         // [4096][1024]
                     __hip_bfloat16* __restrict__ VTw)        // [32][64][2048]
{
    __shared__ __hip_bfloat16 As[128 * 32];
    __shared__ __hip_bfloat16 Bs[128 * 32];

    const int t    = threadIdx.x;
    const int w    = t >> 6;
    const int lane = t & 63;
    const int l15  = lane & 15;
    const int lq   = lane >> 4;
    const int m0   = blockIdx.y * 128;
    const int n0   = blockIdx.x * 128;
    const int wm   = (w >> 1) * 64;
    const int wn   = (w & 1) * 64;
    const int srow = lane >> 2;
    const int scol = (lane & 3) * 8;

    const __hip_bfloat16* A = (n0 < 1024) ? qa16 : ma16;

    float4v acc[4][4];
#pragma unroll
    for (int mi = 0; mi < 4; ++mi)
#pragma unroll
        for (int ni = 0; ni < 4; ++ni) acc[mi][ni] = (float4v){0.f, 0.f, 0.f, 0.f};

    for (int k0 = 0; k0 < 1024; k0 += 32) {
        __syncthreads();
#pragma unroll
        for (int i = 0; i < 2; ++i) {
            const int rr = (w * 2 + i) * 16 + srow;
            GLDS(A  + (size_t)(m0 + rr) * 1024 + k0 + scol, &As[(w * 2 + i) * 512]);
            GLDS(Wt + (size_t)(n0 + rr) * 1024 + k0 + scol, &Bs[(w * 2 + i) * 512]);
        }
        asm volatile("s_waitcnt vmcnt(0)" ::: "memory");
        __syncthreads();

        short8 af[4], bf[4];
#pragma unroll
        for (int mi = 0; mi < 4; ++mi)
            af[mi] = *reinterpret_cast<const short8*>(&As[(wm + mi * 16 + l15) * 32 + lq * 8]);
#pragma unroll
        for (int ni = 0; ni < 4; ++ni)
            bf[ni] = *reinterpret_cast<const short8*>(&Bs[(wn + ni * 16 + l15) * 32 + lq * 8]);
#pragma unroll
        for (int mi = 0; mi < 4; ++mi)
#pragma unroll
            for (int ni = 0; ni < 4; ++ni)
                acc[mi][ni] = __builtin_amdgcn_mfma_f32_16x16x32_bf16(
                    af[mi], bf[ni], acc[mi][ni], 0, 0, 0);
    }

    if (n0 < 2048) {
        __hip_bfloat16* C = (n0 < 1024) ? Qw : Kw;
        const int   nb = (n0 < 1024) ? n0 : n0 - 1024;
        const float al = (n0 < 1024) ? 0.125f : 1.0f;
#pragma unroll
        for (int mi = 0; mi < 4; ++mi)
#pragma unroll
            for (int ni = 0; ni < 4; ++ni)
#pragma unroll
                for (int r = 0; r < 4; ++r) {
                    const int row = m0 + wm + mi * 16 + lq * 4 + r;
                    const int col = nb + wn + ni * 16 + l15;
                    C[(size_t)row * 1024 + col] = (__hip_bfloat16)(acc[mi][ni][r] * al);
                }
    } else {
#pragma unroll
        for (int mi = 0; mi < 4; ++mi) {
            const int rowbase = m0 + wm + mi * 16 + lq * 4;
            const int b   = rowbase >> 11;
            const int seq = rowbase & 2047;
#pragma unroll
            for (int ni = 0; ni < 4; ++ni) {
                const int n = n0 - 2048 + wn + ni * 16 + l15;
                const int h = n >> 6, d = n & 63;
                union { __hip_bfloat16 hh[4]; uint2 v; } pk;
#pragma unroll
                for (int r = 0; r < 4; ++r) pk.hh[r] = (__hip_bfloat16)acc[mi][ni][r];
                *reinterpret_cast<uint2*>(
                    &VTw[((size_t)(b * 16 + h) * 64 + d) * 2048 + seq]) = pk.v;
            }
        }
    }
}

// ---------------------------------------------------------------------------
// Output GEMM: out = X @ Wo, fp32 out. Same m97 staging. grid (8, 32).
// ---------------------------------------------------------------------------
__global__ __launch_bounds__(256)
void gemm_out_kernel(const __hip_bfloat16* __restrict__ Xw,
                     const __hip_bfloat16* __restrict__ Wot,
                     float* __restrict__ out)
{
    __shared__ __hip_bfloat16 As[128 * 32];
    __shared__ __hip_bfloat16 Bs[128 * 32];

    const int t    = threadIdx.x;
    const int w    = t >> 6;
    const int lane = t & 63;
    const int l15  = lane & 15;
    const int lq   = lane >> 4;
    const int m0   = blockIdx.y * 128;
    const int n0   = blockIdx.x * 128;
    const int wm   = (w >> 1) * 64;
    const int wn   = (w & 1) * 64;
    const int srow = lane >> 2;
    const int scol = (lane & 3) * 8;

    float4v acc[4][4];
#pragma unroll
    for (int mi = 0; mi < 4; ++mi)
#pragma unroll
        for (int ni = 0; ni < 4; ++ni) acc[mi][ni] = (float4v){0.f, 0.f, 0.f, 0.f};

    for (int k0 = 0; k0 < 1024; k0 += 32) {
        __syncthreads();
#pragma unroll
        for (int i = 0; i < 2; ++i) {
            const int rr = (w * 2 + i) * 16 + srow;
            GLDS(Xw  + (size_t)(m0 + rr) * 1024 + k0 + scol, &As[(w * 2 + i) * 512]);
            GLDS(Wot + (size_t)(n0 + rr) * 1024 + k0 + scol, &Bs[(w * 2 + i) * 512]);
        }
        asm volatile("s_waitcnt vmcnt(0)" ::: "memory");
        __syncthreads();

        short8 af[4], bf[4];
#pragma unroll
        for (int mi = 0; mi < 4; ++mi)
            af[mi] = *reinterpret_cast<const short8*>(&As[(wm + mi * 16 + l15) * 32 + lq * 8]);
#pragma unroll
        for (int ni = 0; ni < 4; ++ni)
            bf[ni] = *reinterpret_cast<const short8*>(&Bs[(wn + ni * 16 + l15) * 32 + lq * 8]);
#pragma unroll
        for (int mi = 0; mi < 4; ++mi)
#pragma unroll
            for (int ni = 0; ni < 4; ++ni)
                acc[mi][ni] = __builtin_amdgcn_mfma_f32_16x16x32_bf16(
                    af[mi], bf[ni], acc[mi][ni], 0, 0, 0);
    }

#pragma unroll
    for (int mi = 0; mi < 4; ++mi)
#pragma unroll
        for (int ni = 0; ni < 4; ++ni)
#pragma unroll
            for (int r = 0; r < 4; ++r) {
                const int row = m0 + wm + mi * 16 + lq * 4 + r;
                const int col = n0 + wn + ni * 16 + l15;
                out[(size_t)row * 1024 + col] = acc[mi][ni][r];
            }
}

// ---------------------------------------------------------------------------
// Transposed MFMA flash attention, no-max softmax. Grid 512 (XCD swizzle),
// 256 threads = 4 waves; wave w: q-rows [w*32,w*32+32) as 2 groups of 16.
// S^T = K·Q^T (16x16x32); fused per-chunk bias+exp+pack keeps only 8 s-regs
// live; P^T B-frags feed PV (16x16x16_1k) straight from registers.
// launch_bounds(256,2): VGPR cap 256 — round 8 spilled at 112.
// ---------------------------------------------------------------------------
__global__ __launch_bounds__(256, 2)
void attn_kernel(const __hip_bfloat16* __restrict__ Qw,   // [4096][1024]
                 const __hip_bfloat16* __restrict__ Kw,   // [4096][1024]
                 const __hip_bfloat16* __restrict__ VTw,  // [32][64][2048]
                 const float* __restrict__ bias,          // [2048][2048] f32
                 __hip_bfloat16* __restrict__ X)          // [4096][1024]
{
    __shared__ __hip_bfloat16 Ks[128][72];   // [key][dh]
    __shared__ __hip_bfloat16 Vt[64][136];   // [d][key]

    const int t   = threadIdx.x;
    const int w   = t >> 6;
    const int l15 = t & 15;
    const int lq  = (t & 63) >> 4;

    const int bid = blockIdx.x;
    const int r8  = bid & 7;
    const int j   = bid >> 3;
    const int bh  = r8 + 8 * (j >> 4);
    const int q0  = (j & 15) * 128;
    const int b   = bh >> 4;
    const int h   = bh & 15;

    const __hip_bfloat16* Kb  = Kw + (size_t)b * LSEQ * 1024 + h * 64;
    const __hip_bfloat16* VTb = VTw + ((size_t)(b * 16 + h) * 64) * 2048;

    // Q as B-fragments (lane l15 = q-row, lq*8+j = dh) — loop-invariant
    short8 bq[2][2];
#pragma unroll
    for (int g = 0; g < 2; ++g) {
        const __hip_bfloat16* qrow = Qw +
            (size_t)(b * LSEQ + q0 + w * 32 + g * 16 + l15) * 1024 + h * 64 + lq * 8;
        bq[g][0] = *reinterpret_cast<const short8*>(qrow);
        bq[g][1] = *reinterpret_cast<const short8*>(qrow + 32);
    }

    float lpart[2] = {0.f, 0.f};
    float4v o[2][4];
#pragma unroll
    for (int g = 0; g < 2; ++g)
#pragma unroll
        for (int mi = 0; mi < 4; ++mi) o[g][mi] = (float4v){0.f, 0.f, 0.f, 0.f};

    const int skey = t >> 2;
    const int sdh  = (t & 3) * 16;
    const int vd   = t >> 2;
    const int vk   = (t & 3) * 32;

    int4 pk_[2][2], pv_[4];
#pragma unroll
    for (int rnd = 0; rnd < 2; ++rnd) {
        const __hip_bfloat16* ks = Kb + (size_t)(rnd * 64 + skey) * 1024 + sdh;
        pk_[rnd][0] = *reinterpret_cast<const int4*>(ks);
        pk_[rnd][1] = *reinterpret_cast<const int4*>(ks + 8);
    }
#pragma unroll
    for (int c = 0; c < 4; ++c)
        pv_[c] = *reinterpret_cast<const int4*>(VTb + (size_t)vd * 2048 + vk + c * 8);

    for (int kt = 0; kt < LSEQ / 128; ++kt) {
        const int k0 = kt * 128;
        __syncthreads();
#pragma unroll
        for (int rnd = 0; rnd < 2; ++rnd) {
            *reinterpret_cast<int4*>(&Ks[rnd * 64 + skey][sdh])     = pk_[rnd][0];
            *reinterpret_cast<int4*>(&Ks[rnd * 64 + skey][sdh + 8]) = pk_[rnd][1];
        }
#pragma unroll
        for (int c = 0; c < 4; ++c)
            *reinterpret_cast<int4*>(&Vt[vd][vk + c * 8]) = pv_[c];
        {
            const int kn = (kt + 1 < LSEQ / 128) ? k0 + 128 : k0;
#pragma unroll
            for (int rnd = 0; rnd < 2; ++rnd) {
                const __hip_bfloat16* ks = Kb + (size_t)(kn + rnd * 64 + skey) * 1024 + sdh;
                pk_[rnd][0] = *reinterpret_cast<const int4*>(ks);
                pk_[rnd][1] = *reinterpret_cast<const int4*>(ks + 8);
            }
#pragma unroll
            for (int c = 0; c < 4; ++c)
                pv_[c] = *reinterpret_cast<const int4*>(VTb + (size_t)vd * 2048 + kn + vk + c * 8);
        }
        __syncthreads();

        // per 16-key chunk: 4 MFMA -> bias -> exp -> pack (s stays 8 regs)
        short4v pb[2][8];
#pragma unroll
        for (int c = 0; c < 8; ++c) {
            short8 ka0 = *reinterpret_cast<const short8*>(&Ks[c * 16 + l15][lq * 8]);
            short8 ka1 = *reinterpret_cast<const short8*>(&Ks[c * 16 + l15][32 + lq * 8]);
            float4v s0 = (float4v){0.f, 0.f, 0.f, 0.f};
            float4v s1 = (float4v){0.f, 0.f, 0.f, 0.f};
            s0 = __builtin_amdgcn_mfma_f32_16x16x32_bf16(ka0, bq[0][0], s0, 0, 0, 0);
            s0 = __builtin_amdgcn_mfma_f32_16x16x32_bf16(ka1, bq[0][1], s0, 0, 0, 0);
            s1 = __builtin_amdgcn_mfma_f32_16x16x32_bf16(ka0, bq[1][0], s1, 0, 0, 0);
            s1 = __builtin_amdgcn_mfma_f32_16x16x32_bf16(ka1, bq[1][1], s1, 0, 0, 0);
#pragma unroll
            for (int g = 0; g < 2; ++g) {
                const float4v sg = g ? s1 : s0;
                const float* bp = bias +
                    (size_t)(q0 + w * 32 + g * 16 + l15) * LSEQ + k0 + c * 16 + lq * 4;
                float4 bvv = *reinterpret_cast<const float4*>(bp);
                const float* bv = reinterpret_cast<const float*>(&bvv);
                union { __hip_bfloat16 hh[4]; short4v v; } pkk;
                float acc_l = 0.f;
#pragma unroll
                for (int r = 0; r < 4; ++r) {
                    const float p = __expf(sg[r] + bv[r]);
                    acc_l += p;
                    pkk.hh[r] = (__hip_bfloat16)p;
                }
                lpart[g] += acc_l;
                pb[g][c] = pkk.v;
            }
        }

        // O^T += V^T · P^T : 64 MFMA K=16 (V A-frags shared across groups)
#pragma unroll
        for (int mi = 0; mi < 4; ++mi) {
#pragma unroll
            for (int kk = 0; kk < 8; ++kk) {
                short4v va = *reinterpret_cast<const short4v*>(
                    &Vt[mi * 16 + l15][kk * 16 + lq * 4]);
                o[0][mi] = __builtin_amdgcn_mfma_f32_16x16x16bf16_1k(
                    va, pb[0][kk], o[0][mi], 0, 0, 0);
                o[1][mi] = __builtin_amdgcn_mfma_f32_16x16x16bf16_1k(
                    va, pb[1][kk], o[1][mi], 0, 0, 0);
            }
        }
    }

    // l: sum over quads, normalize, 8B stores
#pragma unroll
    for (int g = 0; g < 2; ++g) {
        float lp = lpart[g];
        lp += __shfl_xor(lp, 16);
        lp += __shfl_xor(lp, 32);
        const float inv = 1.f / lp;
        const size_t xrow = (size_t)(b * LSEQ + q0 + w * 32 + g * 16 + l15) * 1024;
#pragma unroll
        for (int mi = 0; mi < 4; ++mi) {
            union { __hip_bfloat16 hh[4]; uint2 v; } pkk;
#pragma unroll
            for (int r = 0; r < 4; ++r) pkk.hh[r] = (__hip_bfloat16)(o[g][mi][r] * inv);
            *reinterpret_cast<uint2*>(&X[xrow + h * 64 + mi * 16 + lq * 4]) = pkk.v;
        }
    }
}

// ---------------------------------------------------------------------------
extern "C" void kernel_launch(void* const* d_in, const int* in_sizes, int n_in,
                              void* d_out, int out_size, void* d_ws, size_t ws_size,
                              hipStream_t stream)
{
    const float* qa   = (const float*)d_in[0];
    const float* ma   = (const float*)d_in[1];
    const float* bias = (const float*)d_in[2];
    const float* Wq   = (const float*)d_in[3];
    const float* Wk   = (const float*)d_in[4];
    const float* Wv   = (const float*)d_in[5];
    const float* Wo   = (const float*)d_in[6];
    float* out = (float*)d_out;

    // ws (48 MB): [0,8) qa16/Xw | [8,16) ma16 | [16,22) Wt | [22,24) Wot |
    //             [24,32) Qw | [32,40) Kw | [40,48) VTw
    char* wsb = (char*)d_ws;
    __hip_bfloat16* qa16 = (__hip_bfloat16*)(wsb);
    __hip_bfloat16* ma16 = (__hip_bfloat16*)(wsb + (8u  << 20));
    __hip_bfloat16* Wt   = (__hip_bfloat16*)(wsb + (16u << 20));
    __hip_bfloat16* Wot  = (__hip_bfloat16*)(wsb + (22u << 20));
    __hip_bfloat16* Qw   = (__hip_bfloat16*)(wsb + (24u << 20));
    __hip_bfloat16* Kw   = (__hip_bfloat16*)(wsb + (32u << 20));
    __hip_bfloat16* VTw  = (__hip_bfloat16*)(wsb + (40u << 20));
    __hip_bfloat16* Xw   = qa16;   // qa16 dead after QKV GEMM

    convert_kernel<<<dim3(MROWS * DMODEL / (256 * 8), 2), 256, 0, stream>>>(
        qa, ma, qa16, ma16);

    transpose_w_kernel<<<dim3(16, 16, 4), 256, 0, stream>>>(
        Wq, Wk, Wv, Wo,
        Wt, Wt + (size_t)DMODEL * DMODEL, Wt + 2 * (size_t)DMODEL * DMODEL, Wot);

    gemm_qkv_kernel<<<dim3(3072 / 128, MROWS / 128), 256, 0, stream>>>(
        qa16, ma16, Wt, Qw, Kw, VTw);

    attn_kernel<<<dim3(512), 256, 0, stream>>>(Qw, Kw, VTw, bias, Xw);

    gemm_out_kernel<<<dim3(1024 / 128, MROWS / 128), 256, 0, stream>>>(
        Xw, Wot, out);
}